// Round 1
// baseline (224.850 us; speedup 1.0000x reference)
//
#include <hip/hip_runtime.h>
#include <hip/hip_bf16.h>

// MultiheadAttention fused: emb = x@W+b -> split Q,K,V (interleaved e*24+h*3+c) ->
// per (b,h): softmax(QK^T)V -> out [B,S,H*E] fp32.
// B=2 H=8 S=2048 E=64 F=512. Internally f16 MFMA (threshold is 2% of absmax).

using half8  = __attribute__((ext_vector_type(8))) _Float16;
using f32x4  = __attribute__((ext_vector_type(4))) float;
using float4v = __attribute__((ext_vector_type(4))) float;

constexpr int BN = 2, HN = 8, SN = 2048, EN = 64, FN = 512;
constexpr int NCH = 24;                                   // 3 * H
constexpr size_t WB_HALVES = (size_t)FN * NCH * EN;       // 512*1536
constexpr size_t WB_BYTES  = WB_HALVES * 2;               // 1.5 MB
constexpr size_t BP_OFF    = WB_BYTES;                    // 1536 f32
constexpr size_t QKV_OFF   = BP_OFF + 1536 * 4;
constexpr size_t T_ELEMS   = (size_t)BN * HN * SN * EN;   // 2097152 per tensor

// ---------------- kernel 1: repack W[f][j] (j = e*24 + h*3 + c) into
// B-fragment-native layout: Wb[((ch*16+kc)*4+cb)*64+lane)*8 + i], f16.
// frag: lane -> col = cb*16 + (lane&15), k-elem i -> f = kc*32 + (lane>>4)*8 + i
__global__ __launch_bounds__(256) void repack_kernel(
    const float* __restrict__ W, const float* __restrict__ bias,
    _Float16* __restrict__ Wb, float* __restrict__ bp) {
  int t = blockIdx.x * 256 + threadIdx.x;
  if (t < FN * 1536) {
    int j = t % 1536, f = t / 1536;             // coalesced read of W
    int c = j % 3, h = (j / 3) & 7, e = j / 24;
    int kc = f >> 5, fi = f & 31;
    int lane = (fi >> 3) * 16 + (e & 15);
    int i = fi & 7;
    int cb = e >> 4;
    int ch = c * 8 + h;
    size_t dst = ((((size_t)ch * 16 + kc) * 4 + cb) * 64 + lane) * 8 + i;
    Wb[dst] = (_Float16)W[t];
  }
  if (t < 1536) {
    int c = t % 3, h = (t / 3) & 7, e = t / 24;
    bp[(c * 8 + h) * 64 + e] = bias[t];
  }
}

// ---------------- kernel 2: projection GEMM [4096 x 512] @ [512 x 1536]
// grid (64 row-tiles, 6 col-groups of 256 cols = 4 ch). 4 waves, 16 rows each.
__global__ __launch_bounds__(256) void proj_kernel(
    const float* __restrict__ x, const _Float16* __restrict__ Wb,
    const float* __restrict__ bp, _Float16* __restrict__ qkv) {
  int rt = blockIdx.x, cg = blockIdx.y;
  int wave = threadIdx.x >> 6, lane = threadIdx.x & 63;
  int lcol = lane & 15, lg = lane >> 4;
  int row0 = rt * 64 + wave * 16;
  f32x4 acc[4][4] = {};   // [chi][cb]
  const float* xrow = x + (size_t)(row0 + lcol) * FN;
  for (int kc = 0; kc < 16; ++kc) {
    const float4v* xp = (const float4v*)(xrow + kc * 32 + lg * 8);
    float4v x0 = xp[0], x1 = xp[1];
    half8 a;
    #pragma unroll
    for (int i = 0; i < 4; ++i) { a[i] = (_Float16)x0[i]; a[4 + i] = (_Float16)x1[i]; }
    #pragma unroll
    for (int chi = 0; chi < 4; ++chi) {
      int ch = cg * 4 + chi;
      #pragma unroll
      for (int cb = 0; cb < 4; ++cb) {
        half8 bfr = *(const half8*)(Wb + ((((size_t)ch * 16 + kc) * 4 + cb) * 64 + lane) * 8);
        acc[chi][cb] = __builtin_amdgcn_mfma_f32_16x16x32_f16(a, bfr, acc[chi][cb], 0, 0, 0);
      }
    }
  }
  #pragma unroll
  for (int chi = 0; chi < 4; ++chi) {
    int ch = cg * 4 + chi;
    int c = ch >> 3, h = ch & 7;
    _Float16* dst = qkv + (size_t)c * T_ELEMS;
    #pragma unroll
    for (int cb = 0; cb < 4; ++cb) {
      int e = cb * 16 + lcol;
      float bv = bp[ch * 64 + e];
      #pragma unroll
      for (int r = 0; r < 4; ++r) {
        int grow = row0 + lg * 4 + r;             // D row = (lane>>4)*4 + r
        int b = grow >> 11, s = grow & 2047;
        dst[((size_t)(b * HN + h) * SN + s) * EN + e] = (_Float16)(acc[chi][cb][r] + bv);
      }
    }
  }
}

// ---------------- kernel 3: flash attention, one WG per (b,h, 64-row q tile)
// 4 waves x 16 q-rows, KVBLK = 32 keys per iter.
__global__ __launch_bounds__(256) void attn_kernel(
    const _Float16* __restrict__ q_ws, const _Float16* __restrict__ k_ws,
    const _Float16* __restrict__ v_ws, float* __restrict__ out) {
  __shared__ __align__(16) _Float16 k_lds[32 * 72];       // pad 64->72: bank-balanced b128 reads
  __shared__ __align__(16) _Float16 v_lds[32 * 64];       // 128B rows, XOR-swizzled
  __shared__ __align__(16) _Float16 p_lds[4][16 * 32];    // per-wave P transpose, XOR-swizzled

  int bid = blockIdx.x;
  int qt = bid & 31, bh = bid >> 5;
  int wave = threadIdx.x >> 6, lane = threadIdx.x & 63;
  int lcol = lane & 15, lg = lane >> 4;
  int q0 = qt * 64 + wave * 16;

  // Q A-frags: row = lcol, k(e) = eh*32 + lg*8 + i
  const _Float16* qbase = q_ws + ((size_t)bh * SN + q0) * EN;
  half8 qf0 = *(const half8*)(qbase + (size_t)lcol * EN + lg * 8);
  half8 qf1 = *(const half8*)(qbase + (size_t)lcol * EN + 32 + lg * 8);

  const _Float16* kbase = k_ws + (size_t)bh * SN * EN;
  const _Float16* vbase = v_ws + (size_t)bh * SN * EN;

  f32x4 oacc[4] = {};           // [eblk]; row q = lg*4+r, col e = eblk*16+lcol
  float m[4], lsum[4];
  #pragma unroll
  for (int r = 0; r < 4; ++r) { m[r] = -1e30f; lsum[r] = 0.f; }

  int skey = wave * 8 + (lane >> 3);         // staging: each wave loads 8 K + 8 V rows
  int se8 = (lane & 7) * 8;
  int vswz = (se8 * 2) ^ ((skey >> 3) << 5); // spread key-classes {k,k+8,k+16,k+24} across banks

  for (int kv = 0; kv < SN; kv += 32) {
    __syncthreads();
    half8 kr = *(const half8*)(kbase + (size_t)(kv + skey) * EN + se8);
    half8 vr = *(const half8*)(vbase + (size_t)(kv + skey) * EN + se8);
    *(half8*)(k_lds + skey * 72 + se8) = kr;
    *(half8*)((char*)(v_lds + skey * 64) + vswz) = vr;
    __syncthreads();

    // QK^T: S[q][key], two 16-key tiles. B-frag: col=key, k=e.
    f32x4 sc0 = {}, sc1 = {};
    sc0 = __builtin_amdgcn_mfma_f32_16x16x32_f16(qf0, *(const half8*)(k_lds + lcol * 72 + lg * 8), sc0, 0, 0, 0);
    sc0 = __builtin_amdgcn_mfma_f32_16x16x32_f16(qf1, *(const half8*)(k_lds + lcol * 72 + 32 + lg * 8), sc0, 0, 0, 0);
    sc1 = __builtin_amdgcn_mfma_f32_16x16x32_f16(qf0, *(const half8*)(k_lds + (16 + lcol) * 72 + lg * 8), sc1, 0, 0, 0);
    sc1 = __builtin_amdgcn_mfma_f32_16x16x32_f16(qf1, *(const half8*)(k_lds + (16 + lcol) * 72 + 32 + lg * 8), sc1, 0, 0, 0);

    // online softmax: row q = lg*4 + r; cols spread over the 16 lanes of the lg-group
    float scale[4];
    #pragma unroll
    for (int r = 0; r < 4; ++r) {
      float mx = fmaxf(sc0[r], sc1[r]);
      mx = fmaxf(mx, __shfl_xor(mx, 1));
      mx = fmaxf(mx, __shfl_xor(mx, 2));
      mx = fmaxf(mx, __shfl_xor(mx, 4));
      mx = fmaxf(mx, __shfl_xor(mx, 8));
      float mn = fmaxf(m[r], mx);
      scale[r] = __expf(m[r] - mn);
      m[r] = mn;
      lsum[r] *= scale[r];
    }
    #pragma unroll
    for (int eb = 0; eb < 4; ++eb)
      #pragma unroll
      for (int r = 0; r < 4; ++r) oacc[eb][r] *= scale[r];

    // P -> LDS (transpose to A-frag layout), XOR swizzle f(row) = (row>>2)<<4
    _Float16* pw = (_Float16*)p_lds[wave];
    #pragma unroll
    for (int r = 0; r < 4; ++r) {
      int qrow = lg * 4 + r;
      int swz = (qrow & 12) << 2;
      float p0 = __expf(sc0[r] - m[r]);
      float p1 = __expf(sc1[r] - m[r]);
      lsum[r] += p0 + p1;
      *(_Float16*)((char*)pw + qrow * 64 + ((lcol * 2) ^ swz)) = (_Float16)p0;
      *(_Float16*)((char*)pw + qrow * 64 + (((16 + lcol) * 2) ^ swz)) = (_Float16)p1;
    }
    asm volatile("s_waitcnt lgkmcnt(0)" ::: "memory");
    __builtin_amdgcn_sched_barrier(0);

    // PV: A = P (row=q=lcol, k=key=lg*8+i), B = V (k=key, col=e)
    half8 pa = *(const half8*)((char*)pw + lcol * 64 + ((lg * 16) ^ ((lcol & 12) << 2)));
    #pragma unroll
    for (int eb = 0; eb < 4; ++eb) {
      half8 vf;
      #pragma unroll
      for (int i = 0; i < 8; ++i) {
        int key = lg * 8 + i;
        int e = eb * 16 + lcol;
        vf[i] = *(const _Float16*)((char*)(v_lds + key * 64) + ((e * 2) ^ ((key >> 3) << 5)));
      }
      oacc[eb] = __builtin_amdgcn_mfma_f32_16x16x32_f16(pa, vf, oacc[eb], 0, 0, 0);
    }
  }

  // finalize: reduce row-sums across the 16 lanes of each lg-group
  #pragma unroll
  for (int r = 0; r < 4; ++r) {
    float s = lsum[r];
    s += __shfl_xor(s, 1); s += __shfl_xor(s, 2);
    s += __shfl_xor(s, 4); s += __shfl_xor(s, 8);
    lsum[r] = s;
  }
  int b = bh >> 3, h = bh & 7;
  #pragma unroll
  for (int eb = 0; eb < 4; ++eb)
    #pragma unroll
    for (int r = 0; r < 4; ++r) {
      int srow = q0 + lg * 4 + r;
      out[((size_t)(b * SN + srow)) * 512 + h * 64 + eb * 16 + lcol] = oacc[eb][r] / lsum[r];
    }
}

extern "C" void kernel_launch(void* const* d_in, const int* in_sizes, int n_in,
                              void* d_out, int out_size, void* d_ws, size_t ws_size,
                              hipStream_t stream) {
  const float* x    = (const float*)d_in[0];
  const float* W    = (const float*)d_in[1];
  const float* bias = (const float*)d_in[2];
  float* out = (float*)d_out;
  char* ws = (char*)d_ws;
  _Float16* Wb  = (_Float16*)(ws);
  float*    bp  = (float*)(ws + BP_OFF);
  _Float16* qkv = (_Float16*)(ws + QKV_OFF);

  repack_kernel<<<(FN * 1536 + 255) / 256, 256, 0, stream>>>(W, bias, Wb, bp);
  proj_kernel<<<dim3(64, 6), 256, 0, stream>>>(x, Wb, bp, qkv);
  attn_kernel<<<dim3(512), 256, 0, stream>>>(qkv, qkv + T_ELEMS, qkv + 2 * T_ELEMS, out);
}

// Round 4
// 157.270 us; speedup vs baseline: 1.4297x; 1.4297x over previous
//
#include <hip/hip_runtime.h>

// MultiheadAttention fused, v2.2.
// Fixes vs v2.1: vtrans staged only 32/64 rows (uninit LDS -> NaN); re-add
// LDS ordering fences around the P-transpose and O-transpose.
// emb = x@W+b (f16 MFMA) -> Q,K [bh][s][e], V -> V^T [bh][e][s]
// attn: swapped-operand flash attention, direct-from-L2 K/V frags, no barriers.
// B=2 H=8 S=2048 E=64 F=512.

using half8  = __attribute__((ext_vector_type(8))) _Float16;
using f32x4  = __attribute__((ext_vector_type(4))) float;
using float4v = __attribute__((ext_vector_type(4))) float;
using uint2v = __attribute__((ext_vector_type(2))) unsigned int;
using uint4v = __attribute__((ext_vector_type(4))) unsigned int;

constexpr int BN = 2, HN = 8, SN = 2048, EN = 64, FN = 512;
constexpr size_t T_ELEMS = (size_t)BN * HN * SN * EN;      // 2M per tensor

// ws layout: Wb | bp | x16 (aliased by V^T after proj) | QKV
constexpr size_t WB_BYTES = (size_t)24 * 16 * 4 * 64 * 8 * 2;   // 1.5 MB
constexpr size_t BP_OFF   = WB_BYTES;
constexpr size_t X16_OFF  = BP_OFF + 1536 * 4;
constexpr size_t X16_BYTES = (size_t)4096 * 512 * 2;            // 4 MB (== V^T bytes)
constexpr size_t QKV_OFF  = X16_OFF + X16_BYTES;

__device__ inline unsigned int pack2h(float a, float b) {
  auto h = __builtin_amdgcn_cvt_pkrtz(a, b);   // __fp16 ext_vector(2)
  return __builtin_bit_cast(unsigned int, h);
}

// ---------------- kernel 1: W repack (gather: coalesced writes, scattered reads)
// dst: Wb[(((ch*16+kc)*4+cb)*64+lane)*8 + i]; frag: col=cb*16+(lane&15), f=kc*32+(lane>>4)*8+i
__global__ __launch_bounds__(256) void repack_kernel(
    const float* __restrict__ W, const float* __restrict__ bias,
    _Float16* __restrict__ Wb, float* __restrict__ bp) {
  int t = blockIdx.x * 256 + threadIdx.x;          // 98304 threads, one half8 each
  int lane = t & 63;
  int cb = (t >> 6) & 3;
  int kc = (t >> 8) & 15;
  int ch = t >> 12;                                 // 0..23
  int e = cb * 16 + (lane & 15);
  int fb = kc * 32 + (lane >> 4) * 8;
  int c = ch >> 3, h = ch & 7;
  int j = e * 24 + h * 3 + c;
  half8 o;
  #pragma unroll
  for (int i = 0; i < 8; ++i) o[i] = (_Float16)W[(size_t)(fb + i) * 1536 + j];
  *(half8*)(Wb + (size_t)t * 8) = o;
  if (t < 1536) {
    int cc = t % 3, hh = (t / 3) & 7, ee = t / 24;
    bp[(cc * 8 + hh) * 64 + ee] = bias[t];
  }
}

// ---------------- kernel 1b: x -> f16
__global__ __launch_bounds__(256) void x16_kernel(const float* __restrict__ x,
                                                  _Float16* __restrict__ x16) {
  int t = blockIdx.x * 256 + threadIdx.x;          // 262144 threads
  const float4v* src = (const float4v*)(x + (size_t)t * 8);
  float4v a = src[0], b = src[1];
  half8 o;
  #pragma unroll
  for (int i = 0; i < 4; ++i) { o[i] = (_Float16)a[i]; o[4 + i] = (_Float16)b[i]; }
  *(half8*)(x16 + (size_t)t * 8) = o;
}

// ---------------- kernel 2: projection GEMM [4096x512]@[512x1536], grid (64,8)
__global__ __launch_bounds__(256) void proj_kernel(
    const _Float16* __restrict__ x16, const _Float16* __restrict__ Wb,
    const float* __restrict__ bp, _Float16* __restrict__ qkv) {
  int rt = blockIdx.x, cg = blockIdx.y;            // 8 col-groups of 3 ch
  int wave = threadIdx.x >> 6, lane = threadIdx.x & 63;
  int lcol = lane & 15, lg = lane >> 4;
  int row0 = rt * 64 + wave * 16;
  f32x4 acc[3][4] = {};
  const _Float16* xr = x16 + (size_t)(row0 + lcol) * FN;
  for (int kc = 0; kc < 16; ++kc) {
    half8 a = *(const half8*)(xr + kc * 32 + lg * 8);
    #pragma unroll
    for (int chi = 0; chi < 3; ++chi) {
      int ch = cg * 3 + chi;
      #pragma unroll
      for (int cb = 0; cb < 4; ++cb) {
        half8 bfr = *(const half8*)(Wb + ((((size_t)ch * 16 + kc) * 4 + cb) * 64 + lane) * 8);
        acc[chi][cb] = __builtin_amdgcn_mfma_f32_16x16x32_f16(a, bfr, acc[chi][cb], 0, 0, 0);
      }
    }
  }
  #pragma unroll
  for (int chi = 0; chi < 3; ++chi) {
    int ch = cg * 3 + chi;
    int c = ch >> 3, h = ch & 7;
    _Float16* dst = qkv + (size_t)c * T_ELEMS;
    #pragma unroll
    for (int cb = 0; cb < 4; ++cb) {
      int e = cb * 16 + lcol;
      float bv = bp[ch * 64 + e];
      #pragma unroll
      for (int r = 0; r < 4; ++r) {
        int grow = row0 + lg * 4 + r;
        int b = grow >> 11, s = grow & 2047;
        dst[((size_t)(b * HN + h) * SN + s) * EN + e] = (_Float16)(acc[chi][cb][r] + bv);
      }
    }
  }
}

// ---------------- kernel 2b: V [bh][s][e] -> V^T [bh][e][s], 64x64 LDS tiles
__global__ __launch_bounds__(256) void vtrans_kernel(const _Float16* __restrict__ v,
                                                     _Float16* __restrict__ vt) {
  __shared__ _Float16 tl[64 * 65];
  int bh = blockIdx.x >> 5, st = blockIdx.x & 31;
  int t = threadIdx.x;
  int s0 = st * 64;
  int sl = t >> 3, e0 = (t & 7) * 8;
  #pragma unroll
  for (int rr = 0; rr < 2; ++rr) {                  // 2 rows/thread: full 64 rows
    half8 vv = *(const half8*)(v + ((size_t)bh * SN + s0 + sl + rr * 32) * EN + e0);
    #pragma unroll
    for (int i = 0; i < 8; ++i) tl[(sl + rr * 32) * 65 + e0 + i] = vv[i];
  }
  __syncthreads();
  int e = t >> 2, sc = t & 3;
  half8 o0, o1;
  #pragma unroll
  for (int i = 0; i < 8; ++i) o0[i] = tl[(sc * 16 + i) * 65 + e];
  #pragma unroll
  for (int i = 0; i < 8; ++i) o1[i] = tl[(sc * 16 + 8 + i) * 65 + e];
  _Float16* dst = vt + ((size_t)bh * EN + e) * SN + s0 + sc * 16;
  *(half8*)dst = o0;
  *(half8*)(dst + 8) = o1;
}

// ---------------- kernel 3: flash attention, swapped operands, no barriers.
// Wave = 32 q-rows (2 tiles of 16), KVBLK=64, K/V frags direct from global (L2).
// grid 256 (XCD-swizzled), 4 waves/block.
__global__ __launch_bounds__(256, 1) void attn_kernel(
    const _Float16* __restrict__ q_ws, const _Float16* __restrict__ k_ws,
    const _Float16* __restrict__ vt_ws, float* __restrict__ out) {
  __shared__ unsigned int p_lds[4][16 * 32];   // per-wave P^T transpose, chunk-rotated
  __shared__ float o_lds[4][16 * 64];          // per-wave O transpose, rotated

  int lb = (blockIdx.x & 7) * 32 + (blockIdx.x >> 3);   // XCD swizzle (256%8==0)
  int bh = lb >> 4, qt = lb & 15;
  int wave = threadIdx.x >> 6, lane = threadIdx.x & 63;
  int q = lane & 15, g = lane >> 4;
  int q0 = qt * 128 + wave * 32;

  const _Float16* qb  = q_ws  + ((size_t)bh * SN + q0) * EN;
  const _Float16* kb  = k_ws  + (size_t)bh * SN * EN;
  const _Float16* vtb = vt_ws + (size_t)bh * EN * SN;

  // Q^T B-frags: col=q(lane&15), k-elem i -> e = eh*32 + g*8 + i
  half8 qfA[2], qfB[2];
  #pragma unroll
  for (int eh = 0; eh < 2; ++eh) {
    qfA[eh] = *(const half8*)(qb + (size_t)q * EN + eh * 32 + g * 8);
    qfB[eh] = *(const half8*)(qb + (size_t)(16 + q) * EN + eh * 32 + g * 8);
  }

  f32x4 oA[4] = {}, oB[4] = {};   // O^T: col=q, row=e=et*16+g*4+r
  float mA = -3e38f, lA = 0.f, mB = -3e38f, lB = 0.f;
  unsigned int* pw = p_lds[wave];

  half8 kf0[4][2], vf0[4][2], kf1[4][2], vf1[4][2];

  auto loadKV = [&](half8 (&kf)[4][2], half8 (&vf)[4][2], int kvl) {
    #pragma unroll
    for (int kt = 0; kt < 4; ++kt)
      #pragma unroll
      for (int eh = 0; eh < 2; ++eh)
        kf[kt][eh] = *(const half8*)(kb + (size_t)(kvl + kt * 16 + q) * EN + eh * 32 + g * 8);
    #pragma unroll
    for (int et = 0; et < 4; ++et)
      #pragma unroll
      for (int kh = 0; kh < 2; ++kh)
        vf[et][kh] = *(const half8*)(vtb + (size_t)(et * 16 + q) * SN + kvl + kh * 32 + g * 8);
  };

  // softmax + PV for one 16-q tile against 64 keys
  auto process = [&](f32x4 (&s)[4], float& m, float& l, f32x4 (&o)[4],
                     const half8 (&vf)[4][2]) {
    float mx = s[0][0];
    #pragma unroll
    for (int kt = 0; kt < 4; ++kt)
      #pragma unroll
      for (int r = 0; r < 4; ++r) mx = fmaxf(mx, s[kt][r]);
    mx = fmaxf(mx, __shfl_xor(mx, 16));
    mx = fmaxf(mx, __shfl_xor(mx, 32));
    float mn = fmaxf(m, mx);
    float sc = __expf(m - mn);
    m = mn;
    l *= sc;
    #pragma unroll
    for (int et = 0; et < 4; ++et)
      #pragma unroll
      for (int r = 0; r < 4; ++r) o[et][r] *= sc;
    float ps = 0.f;
    #pragma unroll
    for (int kt = 0; kt < 4; ++kt) {
      float p0 = __expf(s[kt][0] - mn), p1 = __expf(s[kt][1] - mn);
      float p2 = __expf(s[kt][2] - mn), p3 = __expf(s[kt][3] - mn);
      ps += (p0 + p1) + (p2 + p3);
      uint2v wv;
      wv.x = pack2h(p0, p1);
      wv.y = pack2h(p2, p3);
      // word w = kt*8 + 2g (keys kt*16+4g..+3); chunk-rotate by q, b64-aligned
      int w = kt * 8 + 2 * g;
      int phys = (((w >> 2) + q) & 7) * 4 + (w & 3);
      *(uint2v*)&pw[q * 32 + phys] = wv;
    }
    l += ps;
    // order: all P writes complete-in-order before reads; block compiler reorder
    asm volatile("s_waitcnt lgkmcnt(0)" ::: "memory");
    __builtin_amdgcn_sched_barrier(0);
    // B-frags: keys kh*32 + g*8 .. +7 -> words kh*16+4g..+3 (chunk c=kh*4+g)
    half8 pf[2];
    #pragma unroll
    for (int kh = 0; kh < 2; ++kh) {
      int c = kh * 4 + g;
      uint4v tv = *(const uint4v*)&pw[q * 32 + ((c + q) & 7) * 4];
      pf[kh] = __builtin_bit_cast(half8, tv);
    }
    __builtin_amdgcn_sched_barrier(0);   // pin reads before next iter's writes (WAR)
    #pragma unroll
    for (int et = 0; et < 4; ++et) {
      o[et] = __builtin_amdgcn_mfma_f32_16x16x32_f16(vf[et][0], pf[0], o[et], 0, 0, 0);
      o[et] = __builtin_amdgcn_mfma_f32_16x16x32_f16(vf[et][1], pf[1], o[et], 0, 0, 0);
    }
  };

  auto step = [&](const half8 (&kf)[4][2], const half8 (&vf)[4][2],
                  half8 (&kfn)[4][2], half8 (&vfn)[4][2], int kvn) {
    f32x4 sA[4], sB[4];
    f32x4 zk = {};
    #pragma unroll
    for (int kt = 0; kt < 4; ++kt) {
      sA[kt] = __builtin_amdgcn_mfma_f32_16x16x32_f16(kf[kt][0], qfA[0], zk, 0, 0, 0);
      sA[kt] = __builtin_amdgcn_mfma_f32_16x16x32_f16(kf[kt][1], qfA[1], sA[kt], 0, 0, 0);
      sB[kt] = __builtin_amdgcn_mfma_f32_16x16x32_f16(kf[kt][0], qfB[0], zk, 0, 0, 0);
      sB[kt] = __builtin_amdgcn_mfma_f32_16x16x32_f16(kf[kt][1], qfB[1], sB[kt], 0, 0, 0);
    }
    loadKV(kfn, vfn, kvn);          // prefetch next tile, hidden under softmax+PV
    process(sA, mA, lA, oA, vf);
    process(sB, mB, lB, oB, vf);
  };

  loadKV(kf0, vf0, 0);
  for (int kv = 0; kv < SN; kv += 128) {
    step(kf0, vf0, kf1, vf1, (kv + 64) & (SN - 1));
    step(kf1, vf1, kf0, vf0, (kv + 128) & (SN - 1));
  }

  // finalize
  lA += __shfl_xor(lA, 16); lA += __shfl_xor(lA, 32);
  lB += __shfl_xor(lB, 16); lB += __shfl_xor(lB, 32);
  float rA = 1.f / lA, rB = 1.f / lB;
  int b = bh >> 3, h = bh & 7;
  float* ow = o_lds[wave];
  // tile A: O^T -> LDS (rotated) -> coalesced rows
  #pragma unroll
  for (int et = 0; et < 4; ++et)
    #pragma unroll
    for (int r = 0; r < 4; ++r) {
      int e = et * 16 + g * 4 + r;
      ow[q * 64 + ((e + q * 4) & 63)] = oA[et][r] * rA;
    }
  __syncthreads();
  #pragma unroll
  for (int qr = 0; qr < 16; ++qr) {
    float vvv = ow[qr * 64 + ((lane + qr * 4) & 63)];
    out[((size_t)b * SN + q0 + qr) * 512 + h * 64 + lane] = vvv;
  }
  __syncthreads();
  // tile B
  #pragma unroll
  for (int et = 0; et < 4; ++et)
    #pragma unroll
    for (int r = 0; r < 4; ++r) {
      int e = et * 16 + g * 4 + r;
      ow[q * 64 + ((e + q * 4) & 63)] = oB[et][r] * rB;
    }
  __syncthreads();
  #pragma unroll
  for (int qr = 0; qr < 16; ++qr) {
    float vvv = ow[qr * 64 + ((lane + qr * 4) & 63)];
    out[((size_t)b * SN + q0 + 16 + qr) * 512 + h * 64 + lane] = vvv;
  }
}

extern "C" void kernel_launch(void* const* d_in, const int* in_sizes, int n_in,
                              void* d_out, int out_size, void* d_ws, size_t ws_size,
                              hipStream_t stream) {
  const float* x    = (const float*)d_in[0];
  const float* W    = (const float*)d_in[1];
  const float* bias = (const float*)d_in[2];
  float* out = (float*)d_out;
  char* ws = (char*)d_ws;
  _Float16* Wb  = (_Float16*)(ws);
  float*    bp  = (float*)(ws + BP_OFF);
  _Float16* x16 = (_Float16*)(ws + X16_OFF);   // aliased by V^T after proj
  _Float16* qkv = (_Float16*)(ws + QKV_OFF);
  _Float16* vt  = (_Float16*)(ws + X16_OFF);

  repack_kernel<<<384, 256, 0, stream>>>(W, bias, Wb, bp);
  x16_kernel<<<1024, 256, 0, stream>>>(x, x16);
  proj_kernel<<<dim3(64, 8), 256, 0, stream>>>(x16, Wb, bp, qkv);
  vtrans_kernel<<<512, 256, 0, stream>>>(qkv + 2 * T_ELEMS, vt);
  attn_kernel<<<256, 256, 0, stream>>>(qkv, qkv + T_ELEMS, vt, out);
}

// Round 5
// 130.893 us; speedup vs baseline: 1.7178x; 1.2015x over previous
//
#include <hip/hip_runtime.h>

// MultiheadAttention fused, v3.
// attn rewritten: LDS-staged K/V (global_load_lds w16, double-buffered, XOR-swizzled),
// grid 512 (16 rows/wave, 8 waves/CU), 2-phase loop, defer-max, setprio.
// B=2 H=8 S=2048 E=64 F=512. f16 MFMA internally.

using half8  = __attribute__((ext_vector_type(8))) _Float16;
using f32x4  = __attribute__((ext_vector_type(4))) float;
using float4v = __attribute__((ext_vector_type(4))) float;
using uint2v = __attribute__((ext_vector_type(2))) unsigned int;
using uint4v = __attribute__((ext_vector_type(4))) unsigned int;

constexpr int BN = 2, HN = 8, SN = 2048, EN = 64, FN = 512;
constexpr size_t T_ELEMS = (size_t)BN * HN * SN * EN;      // 2M per tensor

constexpr size_t WB_BYTES = (size_t)24 * 16 * 4 * 64 * 8 * 2;   // 1.5 MB
constexpr size_t BP_OFF   = WB_BYTES;
constexpr size_t X16_OFF  = BP_OFF + 1536 * 4;
constexpr size_t X16_BYTES = (size_t)4096 * 512 * 2;            // 4 MB (== V^T bytes)
constexpr size_t QKV_OFF  = X16_OFF + X16_BYTES;

__device__ inline unsigned int pack2h(float a, float b) {
  auto h = __builtin_amdgcn_cvt_pkrtz(a, b);
  return __builtin_bit_cast(unsigned int, h);
}

__device__ __forceinline__ void async_copy16(void* lds, const void* g) {
  __builtin_amdgcn_global_load_lds(
      (const __attribute__((address_space(1))) unsigned int*)g,
      (__attribute__((address_space(3))) unsigned int*)lds, 16, 0, 0);
}

// ---------------- kernel 1: W repack (coalesced frag-layout writes)
__global__ __launch_bounds__(256) void repack_kernel(
    const float* __restrict__ W, const float* __restrict__ bias,
    _Float16* __restrict__ Wb, float* __restrict__ bp) {
  int t = blockIdx.x * 256 + threadIdx.x;
  int lane = t & 63;
  int cb = (t >> 6) & 3;
  int kc = (t >> 8) & 15;
  int ch = t >> 12;
  int e = cb * 16 + (lane & 15);
  int fb = kc * 32 + (lane >> 4) * 8;
  int c = ch >> 3, h = ch & 7;
  int j = e * 24 + h * 3 + c;
  half8 o;
  #pragma unroll
  for (int i = 0; i < 8; ++i) o[i] = (_Float16)W[(size_t)(fb + i) * 1536 + j];
  *(half8*)(Wb + (size_t)t * 8) = o;
  if (t < 1536) {
    int cc = t % 3, hh = (t / 3) & 7, ee = t / 24;
    bp[(cc * 8 + hh) * 64 + ee] = bias[t];
  }
}

// ---------------- kernel 1b: x -> f16
__global__ __launch_bounds__(256) void x16_kernel(const float* __restrict__ x,
                                                  _Float16* __restrict__ x16) {
  int t = blockIdx.x * 256 + threadIdx.x;
  const float4v* src = (const float4v*)(x + (size_t)t * 8);
  float4v a = src[0], b = src[1];
  half8 o;
  #pragma unroll
  for (int i = 0; i < 4; ++i) { o[i] = (_Float16)a[i]; o[4 + i] = (_Float16)b[i]; }
  *(half8*)(x16 + (size_t)t * 8) = o;
}

// ---------------- kernel 2: projection GEMM [4096x512]@[512x1536], grid (64,8)
__global__ __launch_bounds__(256) void proj_kernel(
    const _Float16* __restrict__ x16, const _Float16* __restrict__ Wb,
    const float* __restrict__ bp, _Float16* __restrict__ qkv) {
  int rt = blockIdx.x, cg = blockIdx.y;
  int wave = threadIdx.x >> 6, lane = threadIdx.x & 63;
  int lcol = lane & 15, lg = lane >> 4;
  int row0 = rt * 64 + wave * 16;
  f32x4 acc[3][4] = {};
  const _Float16* xr = x16 + (size_t)(row0 + lcol) * FN;
  for (int kc = 0; kc < 16; ++kc) {
    half8 a = *(const half8*)(xr + kc * 32 + lg * 8);
    #pragma unroll
    for (int chi = 0; chi < 3; ++chi) {
      int ch = cg * 3 + chi;
      #pragma unroll
      for (int cb = 0; cb < 4; ++cb) {
        half8 bfr = *(const half8*)(Wb + ((((size_t)ch * 16 + kc) * 4 + cb) * 64 + lane) * 8);
        acc[chi][cb] = __builtin_amdgcn_mfma_f32_16x16x32_f16(a, bfr, acc[chi][cb], 0, 0, 0);
      }
    }
  }
  #pragma unroll
  for (int chi = 0; chi < 3; ++chi) {
    int ch = cg * 3 + chi;
    int c = ch >> 3, h = ch & 7;
    _Float16* dst = qkv + (size_t)c * T_ELEMS;
    #pragma unroll
    for (int cb = 0; cb < 4; ++cb) {
      int e = cb * 16 + lcol;
      float bv = bp[ch * 64 + e];
      #pragma unroll
      for (int r = 0; r < 4; ++r) {
        int grow = row0 + lg * 4 + r;
        int b = grow >> 11, s = grow & 2047;
        dst[((size_t)(b * HN + h) * SN + s) * EN + e] = (_Float16)(acc[chi][cb][r] + bv);
      }
    }
  }
}

// ---------------- kernel 2b: V [bh][s][e] -> V^T [bh][e][s]
__global__ __launch_bounds__(256) void vtrans_kernel(const _Float16* __restrict__ v,
                                                     _Float16* __restrict__ vt) {
  __shared__ _Float16 tl[64 * 65];
  int bh = blockIdx.x >> 5, st = blockIdx.x & 31;
  int t = threadIdx.x;
  int s0 = st * 64;
  int sl = t >> 3, e0 = (t & 7) * 8;
  #pragma unroll
  for (int rr = 0; rr < 2; ++rr) {
    half8 vv = *(const half8*)(v + ((size_t)bh * SN + s0 + sl + rr * 32) * EN + e0);
    #pragma unroll
    for (int i = 0; i < 8; ++i) tl[(sl + rr * 32) * 65 + e0 + i] = vv[i];
  }
  __syncthreads();
  int e = t >> 2, sc = t & 3;
  half8 o0, o1;
  #pragma unroll
  for (int i = 0; i < 8; ++i) o0[i] = tl[(sc * 16 + i) * 65 + e];
  #pragma unroll
  for (int i = 0; i < 8; ++i) o1[i] = tl[(sc * 16 + 8 + i) * 65 + e];
  _Float16* dst = vt + ((size_t)bh * EN + e) * SN + s0 + sc * 16;
  *(half8*)dst = o0;
  *(half8*)(dst + 8) = o1;
}

// ---------------- kernel 3: flash attention v3.
// grid 512 = 16 bh x 32 q-blocks (64 rows). 4 waves x 16 q-rows.
// K tile [64 key][64 e] and V^T tile [64 e][64 key] staged in LDS (double buffer),
// XOR-swizzled (byte ^= (row&7)<<4), filled by global_load_lds w16 with
// pre-swizzled global source (linear LDS dest).
__global__ __launch_bounds__(256, 2) void attn_kernel(
    const _Float16* __restrict__ q_ws, const _Float16* __restrict__ k_ws,
    const _Float16* __restrict__ vt_ws, float* __restrict__ out) {
  // [0,32768): K/V double buffer: buf c at c*16384 (K @+0, V @+8192)
  // [32768,40960): per-wave P transpose (2 KB each)
  // epilogue: per-wave O transpose 4 KB at wave*4096 (aliases KV bufs, after final barrier)
  __shared__ __align__(16) char smem[40960];

  int bid = blockIdx.x;
  int lb = (bid & 7) * 64 + (bid >> 3);          // XCD swizzle (512 % 8 == 0)
  int bh = lb >> 5, qblk = lb & 31;
  int wave = threadIdx.x >> 6, lane = threadIdx.x & 63;
  int q = lane & 15, g = lane >> 4;
  int q0 = qblk * 64 + wave * 16;

  const _Float16* qb  = q_ws  + ((size_t)bh * SN + q0) * EN;
  const _Float16* kb  = k_ws  + (size_t)bh * SN * EN;
  const _Float16* vtb = vt_ws + (size_t)bh * EN * SN;

  // Q^T B-frags: col=q, k-elem i -> e = eh*32 + g*8 + i
  half8 qf[2];
  qf[0] = *(const half8*)(qb + (size_t)q * EN + g * 8);
  qf[1] = *(const half8*)(qb + (size_t)q * EN + 32 + g * 8);

  f32x4 o[4] = {};                  // O^T: col=q, row e = et*16 + g*4 + r
  float m = -3e38f, l = 0.f;
  unsigned int* pw = (unsigned int*)(smem + 32768 + wave * 2048);

  // staging geometry: dest linear d = i*1024 + lane*16; row = i*8 + (lane>>3);
  // inverse-swizzled source column: ((lane&7) ^ (lane>>3)) * 8 halves
  int sub = lane >> 3;
  int off8 = ((lane & 7) ^ sub) * 8;
  int lin = lane * 16;

  auto stage = [&](int c, int t) {
    char* kbuf = smem + c * 16384;
    char* vbuf = kbuf + 8192;
    int kv = t * 64;
    #pragma unroll
    for (int ii = 0; ii < 2; ++ii) {
      int i = wave * 2 + ii;
      int row = i * 8 + sub;
      async_copy16(kbuf + i * 1024 + lin, kb + (size_t)(kv + row) * EN + off8);
      async_copy16(vbuf + i * 1024 + lin, vtb + (size_t)row * SN + kv + off8);
    }
  };

  stage(0, 0);
  asm volatile("s_waitcnt vmcnt(0)" ::: "memory");
  __syncthreads();

  int qx = (q & 7) << 4;
  for (int t = 0; t < 32; ++t) {
    int c = t & 1;
    if (t + 1 < 32) stage(c ^ 1, t + 1);        // issue next-tile loads early
    const char* kbuf = smem + c * 16384;
    const char* vbuf = kbuf + 8192;

    // frag reads (swizzled): K row=key, V^T row=e; row&7 == q&7 for both
    half8 kf[4][2], vf[4][2];
    #pragma unroll
    for (int kt = 0; kt < 4; ++kt)
      #pragma unroll
      for (int eh = 0; eh < 2; ++eh)
        kf[kt][eh] = *(const half8*)(kbuf + ((((kt * 16 + q) * 128) + eh * 64 + g * 16) ^ qx));
    #pragma unroll
    for (int et = 0; et < 4; ++et)
      #pragma unroll
      for (int kh = 0; kh < 2; ++kh)
        vf[et][kh] = *(const half8*)(vbuf + ((((et * 16 + q) * 128) + kh * 64 + g * 16) ^ qx));

    // QK^T: S^T[key][q]
    f32x4 s[4];
    f32x4 z = {};
    __builtin_amdgcn_s_setprio(1);
    #pragma unroll
    for (int kt = 0; kt < 4; ++kt) {
      s[kt] = __builtin_amdgcn_mfma_f32_16x16x32_f16(kf[kt][0], qf[0], z, 0, 0, 0);
      s[kt] = __builtin_amdgcn_mfma_f32_16x16x32_f16(kf[kt][1], qf[1], s[kt], 0, 0, 0);
    }
    __builtin_amdgcn_s_setprio(0);

    // online softmax with defer-max (THR=8)
    float mx = s[0][0];
    #pragma unroll
    for (int kt = 0; kt < 4; ++kt)
      #pragma unroll
      for (int r = 0; r < 4; ++r) mx = fmaxf(mx, s[kt][r]);
    mx = fmaxf(mx, __shfl_xor(mx, 16));
    mx = fmaxf(mx, __shfl_xor(mx, 32));
    if (!__all(mx <= m + 8.f)) {
      float mn = fmaxf(m, mx);
      float scl = __expf(m - mn);
      m = mn;
      l *= scl;
      #pragma unroll
      for (int et = 0; et < 4; ++et)
        #pragma unroll
        for (int r = 0; r < 4; ++r) o[et][r] *= scl;
    }
    float ps = 0.f;
    #pragma unroll
    for (int kt = 0; kt < 4; ++kt) {
      float p0 = __expf(s[kt][0] - m), p1 = __expf(s[kt][1] - m);
      float p2 = __expf(s[kt][2] - m), p3 = __expf(s[kt][3] - m);
      ps += (p0 + p1) + (p2 + p3);
      uint2v wv;
      wv.x = pack2h(p0, p1);
      wv.y = pack2h(p2, p3);
      int w = kt * 8 + 2 * g;                  // chunk-rotated P^T transpose
      int phys = (((w >> 2) + q) & 7) * 4 + (w & 3);
      *(uint2v*)&pw[q * 32 + phys] = wv;
    }
    l += ps;
    asm volatile("s_waitcnt lgkmcnt(0)" ::: "memory");
    __builtin_amdgcn_sched_barrier(0);
    half8 pf[2];
    #pragma unroll
    for (int kh = 0; kh < 2; ++kh) {
      int cc = kh * 4 + g;
      uint4v tv = *(const uint4v*)&pw[q * 32 + ((cc + q) & 7) * 4];
      pf[kh] = __builtin_bit_cast(half8, tv);
    }
    __builtin_amdgcn_sched_barrier(0);
    __builtin_amdgcn_s_setprio(1);
    #pragma unroll
    for (int et = 0; et < 4; ++et) {
      o[et] = __builtin_amdgcn_mfma_f32_16x16x32_f16(vf[et][0], pf[0], o[et], 0, 0, 0);
      o[et] = __builtin_amdgcn_mfma_f32_16x16x32_f16(vf[et][1], pf[1], o[et], 0, 0, 0);
    }
    __builtin_amdgcn_s_setprio(0);

    asm volatile("s_waitcnt vmcnt(0)" ::: "memory");   // next-tile stage landed
    __syncthreads();
  }

  // epilogue: O^T -> per-wave LDS transpose (aliases KV bufs) -> coalesced stores
  l += __shfl_xor(l, 16);
  l += __shfl_xor(l, 32);
  float rl = 1.f / l;
  int b = bh >> 3, h = bh & 7;
  float* ow = (float*)(smem + wave * 4096);
  #pragma unroll
  for (int et = 0; et < 4; ++et)
    #pragma unroll
    for (int r = 0; r < 4; ++r) {
      int e = et * 16 + g * 4 + r;
      ow[q * 64 + ((e + q * 4) & 63)] = o[et][r] * rl;
    }
  asm volatile("s_waitcnt lgkmcnt(0)" ::: "memory");
  __builtin_amdgcn_sched_barrier(0);
  #pragma unroll
  for (int qr = 0; qr < 16; ++qr) {
    float vvv = ow[qr * 64 + ((lane + qr * 4) & 63)];
    out[((size_t)b * SN + q0 + qr) * 512 + h * 64 + lane] = vvv;
  }
}

extern "C" void kernel_launch(void* const* d_in, const int* in_sizes, int n_in,
                              void* d_out, int out_size, void* d_ws, size_t ws_size,
                              hipStream_t stream) {
  const float* x    = (const float*)d_in[0];
  const float* W    = (const float*)d_in[1];
  const float* bias = (const float*)d_in[2];
  float* out = (float*)d_out;
  char* ws = (char*)d_ws;
  _Float16* Wb  = (_Float16*)(ws);
  float*    bp  = (float*)(ws + BP_OFF);
  _Float16* x16 = (_Float16*)(ws + X16_OFF);   // aliased by V^T after proj
  _Float16* qkv = (_Float16*)(ws + QKV_OFF);
  _Float16* vt  = (_Float16*)(ws + X16_OFF);

  repack_kernel<<<384, 256, 0, stream>>>(W, bias, Wb, bp);
  x16_kernel<<<1024, 256, 0, stream>>>(x, x16);
  proj_kernel<<<dim3(64, 8), 256, 0, stream>>>(x16, Wb, bp, qkv);
  vtrans_kernel<<<512, 256, 0, stream>>>(qkv + 2 * T_ELEMS, vt);
  attn_kernel<<<512, 256, 0, stream>>>(qkv, qkv + T_ELEMS, vt, out);
}